// Round 3
// baseline (17699.495 us; speedup 1.0000x reference)
//
#include <hip/hip_runtime.h>

typedef _Float16 half_t;
typedef _Float16 half8 __attribute__((ext_vector_type(8)));
typedef _Float16 half4v __attribute__((ext_vector_type(4)));
typedef float f32x4 __attribute__((ext_vector_type(4)));

#define DI __device__ __forceinline__

constexpr int Bsz = 256;   // batch
constexpr int Tsz = 128;   // seq len
constexpr int Fsz = 32;    // feature
constexpr int Hsz = 1024;  // hidden
constexpr int NG  = 4096;  // 4*H gate rows
constexpr int K1  = 1152;  // padded 1024+32 (pad zeroed)
constexpr int K2  = 2048;  // 1024+1024
constexpr int RSTR = 84;   // LDS reduce stride (16B-aligned rows, ~2-way banks, 86KB -> 1 block/CU)

// Gate permutation: tile nt (64 gate-rows) holds all 4 gates for 16 hidden units.
DI int perm_to_orig(int np) {
    int nt = np >> 6, r = np & 63, g = r >> 4, jo = r & 15;
    return g * Hsz + nt * 16 + jo;
}

// ---- MFMA fragment-packed layouts (lane-contiguous, 1KB per wave-load) ----
DI size_t wfrag(int np, int k) {
    return ((size_t)((k >> 5) * 256 + (np >> 4)) * 64 + ((k >> 3) & 3) * 16 + (np & 15)) * 8 + (k & 7);
}
DI size_t afrag(int b, int k) {
    return ((size_t)((k >> 5) * 16 + (b >> 4)) * 64 + ((k >> 3) & 3) * 16 + (b & 15)) * 8 + (k & 7);
}

// ---------------- prep kernels ----------------

__global__ void pack_cat(half_t* __restrict__ dst, const float* __restrict__ srcA, int KA,
                         const float* __restrict__ srcB, int KB, int KP) {
    int tid = threadIdx.x;
    int np = blockIdx.y * 64 + (tid & 63);
    int k0 = (blockIdx.x * 4 + (tid >> 6)) * 8;
    if (k0 >= KP) return;
    int n = perm_to_orig(np);
    half8 v;
#pragma unroll
    for (int j = 0; j < 8; ++j) {
        int k = k0 + j;
        float f = 0.f;
        if (k < KA) f = srcA[(size_t)n * KA + k];
        else if (k < KA + KB) f = srcB[(size_t)n * KB + (k - KA)];
        v[j] = (half_t)f;
    }
    *(half8*)(dst + wfrag(np, k0)) = v;
}

__global__ void pack_fold(half_t* __restrict__ dst, const float* __restrict__ Wih0,
                          const float* __restrict__ linW) {
    __shared__ float lw[32][128];
    __shared__ float wi[16][32];
    int nb = blockIdx.x * 16;
    int jb = blockIdx.y * 128;
    int t = threadIdx.x;
    for (int i = t; i < 32 * 128; i += 256) { int f = i >> 7, j = i & 127; lw[f][j] = linW[f * Hsz + jb + j]; }
    for (int i = t; i < 16 * 32; i += 256) { int r = i >> 5, f = i & 31; wi[r][f] = Wih0[perm_to_orig(nb + r) * 32 + f]; }
    __syncthreads();
    int r = t >> 4, j0 = (t & 15) * 8;
    half8 v;
#pragma unroll
    for (int jj = 0; jj < 8; ++jj) {
        float s = 0.f;
#pragma unroll
        for (int f = 0; f < 32; ++f) s += wi[r][f] * lw[f][j0 + jj];
        v[jj] = (half_t)s;
    }
    *(half8*)(dst + wfrag(nb + r, 1024 + jb + j0)) = v;
}

__global__ void pack_bias(float* __restrict__ b5, const float* eb0, const float* eb1,
                          const float* db0, const float* db1, const float* dWih0,
                          const float* linb) {
    int idx = blockIdx.x * 256 + threadIdx.x;
    if (idx >= 5 * NG) return;
    int which = idx >> 12, np = idx & (NG - 1);
    int n = perm_to_orig(np);
    float v;
    if (which == 0) v = eb0[n];
    else if (which == 1) v = eb1[n];
    else if (which == 2) v = db0[n];
    else if (which == 3) {
        v = db0[n];
        for (int f = 0; f < 32; ++f) v += dWih0[n * 32 + f] * linb[f];
    } else v = db1[n];
    b5[idx] = v;
}

__global__ void pack_small(half_t* __restrict__ Wlin, half_t* __restrict__ bufA0,
                           const float* __restrict__ linW, const float* __restrict__ inseq) {
    int idx = blockIdx.x * 256 + threadIdx.x;
    if (idx < 32 * Hsz) Wlin[idx] = (half_t)linW[idx];
    if (idx < Bsz * 4) {
        int b = idx >> 2, fg = idx & 3;
        half8 v;
#pragma unroll
        for (int j = 0; j < 8; ++j) v[j] = (half_t)inseq[(size_t)b * (Tsz * Fsz) + fg * 8 + j];
        *(half8*)(bufA0 + afrag(b, 1024 + fg * 8)) = v;
    }
}

// ---------------- megakernel: all 512 phases, persistent, group barriers ----------------

struct MegaArgs {
    const float* in_seq;
    const half_t *Wenc1, *Wenc2, *Wdec1a, *Wdec1b, *Wdec2;
    const float *be1, *be2, *bd1a, *bd1b, *bd2;
    float *c0, *c1;
    half_t *bufA0, *bufA1, *bufB0, *bufB1, *bufD0, *bufD1, *H1hist;
    unsigned* cnt;
};

struct PhaseDesc {
    const half_t* A; const half_t* W; const float* bias; float* c;
    half_t* h0; int cb0; half_t* h1; int cb1; half_t* h2; int cb2;
    const float* xs; half_t* xd; int K;
};

DI PhaseDesc make_desc(int p, const MegaArgs& g) {
    PhaseDesc d = {};
    const half_t* bufA[2] = {g.bufA0, g.bufA1};
    half_t* bufAm[2] = {g.bufA0, g.bufA1};
    half_t* bufB[2] = {g.bufB0, g.bufB1};
    half_t* bufD[2] = {g.bufD0, g.bufD1};
    if (p < 256) {
        int t = p >> 1, pp = t & 1;
        if ((p & 1) == 0) {  // enc layer0
            d.A = bufA[pp]; d.W = g.Wenc1; d.bias = g.be1; d.c = g.c0;
            d.h0 = bufB[pp]; d.cb0 = 0; d.h1 = bufAm[pp ^ 1]; d.cb1 = 0;
            d.K = K1;
        } else {  // enc layer1 (+ stage x_{t+1})
            int tsel = (t + 1 < Tsz) ? t + 1 : Tsz - 1;
            d.A = bufB[pp]; d.W = g.Wenc2; d.bias = g.be2; d.c = g.c1;
            d.h0 = bufB[pp ^ 1]; d.cb0 = 1024;
            d.xs = g.in_seq + (size_t)tsel * Fsz; d.xd = bufAm[pp ^ 1];
            d.K = K2;
        }
    } else if (p == 256) {  // dec t=0 layer0: A = [h0_enc | x_last]
        d.A = g.bufA0; d.W = g.Wdec1a; d.bias = g.bd1a; d.c = g.c0;
        d.h0 = g.bufB0; d.cb0 = 0; d.h1 = g.bufD1; d.cb1 = 0;
        d.K = K1;
    } else if (p == 257) {  // dec t=0 layer1
        d.A = g.bufB0; d.W = g.Wdec2; d.bias = g.bd2; d.c = g.c1;
        d.h0 = g.bufB1; d.cb0 = 1024; d.h1 = g.bufD1; d.cb1 = 1024;
        d.h2 = g.H1hist; d.cb2 = 0;
        d.K = K2;
    } else {
        int t = (p - 256) >> 1, q = t & 1;
        if ((p & 1) == 0) {  // dec layer0 (folded feedback): A = [h0_prev | h1_prev]
            d.A = bufD[q]; d.W = g.Wdec1b; d.bias = g.bd1b; d.c = g.c0;
            d.h0 = bufB[q]; d.cb0 = 0; d.h1 = bufD[q ^ 1]; d.cb1 = 0;
            d.K = K2;
        } else {  // dec layer1
            d.A = bufB[q]; d.W = g.Wdec2; d.bias = g.bd2; d.c = g.c1;
            d.h0 = bufB[q ^ 1]; d.cb0 = 1024; d.h1 = bufD[q ^ 1]; d.cb1 = 1024;
            d.h2 = g.H1hist + (size_t)t * Bsz * Hsz; d.cb2 = 0;
            d.K = K2;
        }
    }
    return d;
}

template <int K>
DI void run_phase(const PhaseDesc& d, int mt, int nt, int tid,
                  unsigned* cnt, unsigned waitTarget,
                  float (&red)[4][64][RSTR]) {
    constexpr int CHW = (K / 32) / 4;  // k-chunks per wave: 9 (K1) or 16 (K2)
    int lane = tid & 63, w = tid >> 6;
    const half_t* pa = d.A + ((size_t)((w * CHW) * 16 + mt * 4) * 64 + lane) * 8;
    const half_t* pw = d.W + ((size_t)((w * CHW) * 256 + nt * 4) * 64 + lane) * 8;

    f32x4 acc[4][4] = {};
    half8 bA[3][4], bW[3][4];

#define LOADW(st, kk)                                                              \
    {                                                                              \
        _Pragma("unroll") for (int ni = 0; ni < 4; ++ni)                           \
            bW[st][ni] = *(const half8*)(pw + (size_t)(kk) * 131072 + ni * 512);   \
    }
#define LOADA(st, kk)                                                              \
    {                                                                              \
        _Pragma("unroll") for (int mi = 0; mi < 4; ++mi)                           \
            bA[st][mi] = *(const half8*)(pa + (size_t)(kk) * 8192 + mi * 512);     \
    }

    // W prefetch is barrier-safe (weights are constant) — hide spin latency
    LOADW(0, 0)
    LOADW(1, 1)

    if (waitTarget) {
        if (tid == 0) {
            while (__hip_atomic_load(cnt, __ATOMIC_RELAXED, __HIP_MEMORY_SCOPE_AGENT) < waitTarget)
                __builtin_amdgcn_s_sleep(1);
            __threadfence();  // acquire: invalidate stale L1/L2 before A loads
        }
        __syncthreads();
    }

    LOADA(0, 0)
    LOADA(1, 1)
#pragma unroll
    for (int kk = 0; kk < CHW; ++kk) {
        if (kk + 2 < CHW) { LOADW((kk + 2) % 3, kk + 2) LOADA((kk + 2) % 3, kk + 2) }
        const int st = kk % 3;
#pragma unroll
        for (int mi = 0; mi < 4; ++mi)
#pragma unroll
            for (int ni = 0; ni < 4; ++ni)
                acc[mi][ni] = __builtin_amdgcn_mfma_f32_16x16x32_f16(bA[st][mi], bW[st][ni], acc[mi][ni], 0, 0, 0);
    }
#undef LOADW
#undef LOADA

    // cross-wave K reduction via LDS
    int l15 = lane & 15, l4 = lane >> 4;
#pragma unroll
    for (int mi = 0; mi < 4; ++mi)
#pragma unroll
        for (int ni = 0; ni < 4; ++ni)
#pragma unroll
            for (int r = 0; r < 4; ++r)
                red[w][mi * 16 + l4 * 4 + r][ni * 16 + l15] = acc[mi][ni][r];
    __syncthreads();

    // fused LSTM epilogue: thread -> (1 row, 4 hidden units)
    int row = tid >> 2, q = tid & 3, jo0 = q * 4;
    f32x4 g0 = {}, g1 = {}, g2 = {}, g3 = {};
#pragma unroll
    for (int ww = 0; ww < 4; ++ww) {
        g0 += *(const f32x4*)&red[ww][row][jo0];
        g1 += *(const f32x4*)&red[ww][row][16 + jo0];
        g2 += *(const f32x4*)&red[ww][row][32 + jo0];
        g3 += *(const f32x4*)&red[ww][row][48 + jo0];
    }
    const float* bb = d.bias + nt * 64;
    g0 += *(const f32x4*)(bb + jo0);
    g1 += *(const f32x4*)(bb + 16 + jo0);
    g2 += *(const f32x4*)(bb + 32 + jo0);
    g3 += *(const f32x4*)(bb + 48 + jo0);

    int bglob = mt * 64 + row;
    int jg0 = nt * 16 + jo0;
    float* cp = d.c + (size_t)bglob * Hsz + jg0;
    f32x4 cold = *(const f32x4*)cp;
    f32x4 cnew;
    half4v hv;
#pragma unroll
    for (int e = 0; e < 4; ++e) {
        float si = 1.f / (1.f + __expf(-g0[e]));
        float sf = 1.f / (1.f + __expf(-g1[e]));
        float tg = 1.f - 2.f / (__expf(2.f * g2[e]) + 1.f);
        float so = 1.f / (1.f + __expf(-g3[e]));
        float cn = sf * cold[e] + si * tg;
        cnew[e] = cn;
        float th = 1.f - 2.f / (__expf(2.f * cn) + 1.f);
        hv[e] = (half_t)(so * th);
    }
    *(f32x4*)cp = cnew;

    {
        int col = d.cb0 + jg0;
        *(half4v*)(d.h0 + ((size_t)((col >> 5) * 16 + (bglob >> 4)) * 64 + ((col >> 3) & 3) * 16 + (bglob & 15)) * 8 + (col & 7)) = hv;
    }
    if (d.h1) {
        int col = d.cb1 + jg0;
        *(half4v*)(d.h1 + ((size_t)((col >> 5) * 16 + (bglob >> 4)) * 64 + ((col >> 3) & 3) * 16 + (bglob & 15)) * 8 + (col & 7)) = hv;
    }
    if (d.h2) {
        int col = d.cb2 + jg0;
        *(half4v*)(d.h2 + ((size_t)((col >> 5) * 16 + (bglob >> 4)) * 64 + ((col >> 3) & 3) * 16 + (bglob & 15)) * 8 + (col & 7)) = hv;
    }

    // stage next encoder input x (f32 -> f16 frag cols 1024..1056); nt==0 WGs only
    if (d.xs && nt == 0) {
        int f0 = q * 8;
        const float* xs = d.xs + (size_t)bglob * (Tsz * Fsz) + f0;
        half8 v;
#pragma unroll
        for (int j = 0; j < 8; ++j) v[j] = (half_t)xs[j];
        *(half8*)(d.xd + afrag(bglob, 1024 + f0)) = v;
    }
}

__launch_bounds__(256, 1) __global__ void mega_kernel(MegaArgs g) {
    __shared__ __align__(16) float red[4][64][RSTR];  // 86 KB -> 1 block/CU
    int bid = blockIdx.x;
    // XCD swizzle: 4 mt-tiles sharing a weight panel land on one XCD (bid%8 fixed)
    int low3 = bid & 7, rest = bid >> 3;
    int mt = rest & 3, nt = ((rest >> 2) << 3) | low3;
    int tid = threadIdx.x;
    unsigned* cnt = g.cnt + mt * 64;  // one barrier counter per row-block group (64 WGs)

#pragma unroll 1
    for (int p = 0; p < 512; ++p) {
        PhaseDesc d = make_desc(p, g);
        if (d.K == K1) run_phase<K1>(d, mt, nt, tid, cnt, (unsigned)(64 * p), red);
        else           run_phase<K2>(d, mt, nt, tid, cnt, (unsigned)(64 * p), red);
        // arrive: all stores drained at barrier, then tid0 releases + counts
        __syncthreads();
        if (tid == 0) {
            __threadfence();  // release: write back this XCD's dirty lines
            __hip_atomic_fetch_add(cnt, 1u, __ATOMIC_RELEASE, __HIP_MEMORY_SCOPE_AGENT);
        }
    }
}

// ---------------- final projection ----------------
__launch_bounds__(256, 1) __global__
void lin_out(const half_t* __restrict__ H1, const half_t* __restrict__ Wl,
             const float* __restrict__ lb, float* __restrict__ out) {
    int w = threadIdx.x >> 6, lane = threadIdx.x & 63;
    int l15 = lane & 15, l4 = lane >> 4;
    int rowt = blockIdx.x * 4 + w;
    int t = rowt >> 4, mi = rowt & 15;
    const half_t* pa = H1 + (size_t)t * (Bsz * Hsz);
    const half_t* pb0 = Wl + (size_t)l15 * Hsz + l4 * 8;
    const half_t* pb1 = Wl + (size_t)(16 + l15) * Hsz + l4 * 8;
    f32x4 ac0 = {}, ac1 = {};
#pragma unroll 4
    for (int kc = 0; kc < 32; ++kc) {
        half8 a = *(const half8*)(pa + ((size_t)(kc * 16 + mi) * 64 + lane) * 8);
        half8 b0 = *(const half8*)(pb0 + kc * 32);
        half8 b1 = *(const half8*)(pb1 + kc * 32);
        ac0 = __builtin_amdgcn_mfma_f32_16x16x32_f16(a, b0, ac0, 0, 0, 0);
        ac1 = __builtin_amdgcn_mfma_f32_16x16x32_f16(a, b1, ac1, 0, 0, 0);
    }
#pragma unroll
    for (int r = 0; r < 4; ++r) {
        int row = rowt * 16 + l4 * 4 + r;  // flat = t*256 + b
        int b = row & 255;
        size_t o = (size_t)b * (Tsz * Fsz) + t * Fsz;
        out[o + l15] = ac0[r] + lb[l15];
        out[o + 16 + l15] = ac1[r] + lb[16 + l15];
    }
}

// ---------------- host ----------------

extern "C" void kernel_launch(void* const* d_in, const int* in_sizes, int n_in,
                              void* d_out, int out_size, void* d_ws, size_t ws_size,
                              hipStream_t stream) {
    (void)in_sizes; (void)n_in;
    const float* in_seq = (const float*)d_in[0];
    const float* eWih0 = (const float*)d_in[1];
    const float* eWhh0 = (const float*)d_in[2];
    const float* eb0 = (const float*)d_in[3];
    const float* eWih1 = (const float*)d_in[4];
    const float* eWhh1 = (const float*)d_in[5];
    const float* eb1 = (const float*)d_in[6];
    const float* dWih0 = (const float*)d_in[7];
    const float* dWhh0 = (const float*)d_in[8];
    const float* db0 = (const float*)d_in[9];
    const float* dWih1 = (const float*)d_in[10];
    const float* dWhh1 = (const float*)d_in[11];
    const float* db1 = (const float*)d_in[12];
    const float* linW = (const float*)d_in[13];
    const float* linb = (const float*)d_in[14];
    float* out = (float*)d_out;

    char* base = (char*)d_ws;
    size_t off = 0;
    auto alloc = [&](size_t bytes) {
        char* r = base + off;
        off = (off + bytes + 255) & ~(size_t)255;
        return r;
    };
    half_t* Wenc1 = (half_t*)alloc((size_t)NG * K1 * 2);
    half_t* Wenc2 = (half_t*)alloc((size_t)NG * K2 * 2);
    half_t* Wdec1a = (half_t*)alloc((size_t)NG * K1 * 2);
    half_t* Wdec1b = (half_t*)alloc((size_t)NG * K2 * 2);
    half_t* Wdec2 = (half_t*)alloc((size_t)NG * K2 * 2);
    half_t* Wlin = (half_t*)alloc((size_t)32 * Hsz * 2);
    float* bias5 = (float*)alloc((size_t)5 * NG * 4);
    float* c0 = (float*)alloc((size_t)Bsz * Hsz * 4);
    float* c1 = (float*)alloc((size_t)Bsz * Hsz * 4);
    half_t* bufA0 = (half_t*)alloc((size_t)Bsz * K1 * 2);
    half_t* bufA1 = (half_t*)alloc((size_t)Bsz * K1 * 2);
    half_t* bufD0 = (half_t*)alloc((size_t)Bsz * K2 * 2);
    half_t* bufD1 = (half_t*)alloc((size_t)Bsz * K2 * 2);
    half_t* bufB0 = (half_t*)alloc((size_t)Bsz * K2 * 2);
    half_t* bufB1 = (half_t*)alloc((size_t)Bsz * K2 * 2);
    half_t* H1hist = (half_t*)alloc((size_t)Tsz * Bsz * Hsz * 2);
    unsigned* barCnt = (unsigned*)alloc(4 * 64 * sizeof(unsigned));

    if (off > ws_size) {  // clean failure signature: all-zero output
        hipMemsetAsync(d_out, 0, (size_t)out_size * 4, stream);
        return;
    }

    float* be1 = bias5;
    float* be2 = bias5 + NG;
    float* bd1a = bias5 + 2 * NG;
    float* bd1b = bias5 + 3 * NG;
    float* bd2 = bias5 + 4 * NG;

    // ---- prep (re-run every call; graph-replay safe) ----
    hipMemsetAsync(c0, 0, (size_t)Bsz * Hsz * 4, stream);
    hipMemsetAsync(c1, 0, (size_t)Bsz * Hsz * 4, stream);
    hipMemsetAsync(bufA0, 0, (size_t)Bsz * K1 * 2, stream);
    hipMemsetAsync(bufA1, 0, (size_t)Bsz * K1 * 2, stream);
    hipMemsetAsync(bufB0, 0, (size_t)Bsz * K2 * 2, stream);
    hipMemsetAsync(barCnt, 0, 4 * 64 * sizeof(unsigned), stream);

    pack_cat<<<dim3(K1 / 32, NG / 64), 256, 0, stream>>>(Wenc1, eWhh0, 1024, eWih0, 32, K1);
    pack_cat<<<dim3(K2 / 32, NG / 64), 256, 0, stream>>>(Wenc2, eWih1, 1024, eWhh1, 1024, K2);
    pack_cat<<<dim3(K1 / 32, NG / 64), 256, 0, stream>>>(Wdec1a, dWhh0, 1024, dWih0, 32, K1);
    pack_cat<<<dim3(K2 / 32, NG / 64), 256, 0, stream>>>(Wdec1b, dWhh0, 1024, nullptr, 0, K2);
    pack_fold<<<dim3(NG / 16, 1024 / 128), 256, 0, stream>>>(Wdec1b, dWih0, linW);
    pack_cat<<<dim3(K2 / 32, NG / 64), 256, 0, stream>>>(Wdec2, dWih1, 1024, dWhh1, 1024, K2);
    pack_bias<<<(5 * NG + 255) / 256, 256, 0, stream>>>(bias5, eb0, eb1, db0, db1, dWih0, linb);
    pack_small<<<128, 256, 0, stream>>>(Wlin, bufA0, linW, in_seq);

    // ---- all 512 recurrent phases in one cooperative kernel ----
    MegaArgs ma;
    ma.in_seq = in_seq;
    ma.Wenc1 = Wenc1; ma.Wenc2 = Wenc2;
    ma.Wdec1a = Wdec1a; ma.Wdec1b = Wdec1b; ma.Wdec2 = Wdec2;
    ma.be1 = be1; ma.be2 = be2; ma.bd1a = bd1a; ma.bd1b = bd1b; ma.bd2 = bd2;
    ma.c0 = c0; ma.c1 = c1;
    ma.bufA0 = bufA0; ma.bufA1 = bufA1;
    ma.bufB0 = bufB0; ma.bufB1 = bufB1;
    ma.bufD0 = bufD0; ma.bufD1 = bufD1;
    ma.H1hist = H1hist;
    ma.cnt = barCnt;
    void* kargs[] = {&ma};
    hipLaunchCooperativeKernel((const void*)mega_kernel, dim3(256), dim3(256), kargs, 0, stream);

    lin_out<<<512, 256, 0, stream>>>(H1hist, Wlin, linb, out);
}

// Round 4
// 6326.617 us; speedup vs baseline: 2.7976x; 2.7976x over previous
//
#include <hip/hip_runtime.h>

typedef _Float16 half_t;
typedef _Float16 half8 __attribute__((ext_vector_type(8)));
typedef _Float16 half4v __attribute__((ext_vector_type(4)));
typedef float f32x4 __attribute__((ext_vector_type(4)));

#define DI __device__ __forceinline__

constexpr int Bsz = 256;   // batch
constexpr int Tsz = 128;   // seq len
constexpr int Fsz = 32;    // feature
constexpr int Hsz = 1024;  // hidden
constexpr int NG  = 4096;  // 4*H gate rows
constexpr int K1  = 1152;  // padded 1024+32 (pad zeroed)
constexpr int K2  = 2048;  // 1024+1024
constexpr int RSTR = 84;   // LDS reduce stride (86KB -> 1 block/CU)
constexpr int RING = 32;   // ring depth: addr reuse only after 64 phases -> L2 lines provably evicted
constexpr int SZA = Bsz * K1;  // ringA slot elements
constexpr int SZB = Bsz * K2;  // ringB/ringD slot elements

// Gate permutation: tile nt (64 gate-rows) holds all 4 gates for 16 hidden units.
DI int perm_to_orig(int np) {
    int nt = np >> 6, r = np & 63, g = r >> 4, jo = r & 15;
    return g * Hsz + nt * 16 + jo;
}

// ---- MFMA fragment-packed layouts (lane-contiguous, 1KB per wave-load) ----
DI size_t wfrag(int np, int k) {
    return ((size_t)((k >> 5) * 256 + (np >> 4)) * 64 + ((k >> 3) & 3) * 16 + (np & 15)) * 8 + (k & 7);
}
DI size_t afrag(int b, int k) {
    return ((size_t)((k >> 5) * 16 + (b >> 4)) * 64 + ((k >> 3) & 3) * 16 + (b & 15)) * 8 + (k & 7);
}

// write-through (agent-scope) 8B store: lands at the coherence point, no dirty L2 line
DI void store8_wt(half_t* p, half4v v) {
    unsigned long long bits;
    __builtin_memcpy(&bits, &v, 8);
    __hip_atomic_store((unsigned long long*)p, bits, __ATOMIC_RELAXED, __HIP_MEMORY_SCOPE_AGENT);
}

// ---------------- prep kernels ----------------

__global__ void pack_cat(half_t* __restrict__ dst, const float* __restrict__ srcA, int KA,
                         const float* __restrict__ srcB, int KB, int KP) {
    int tid = threadIdx.x;
    int np = blockIdx.y * 64 + (tid & 63);
    int k0 = (blockIdx.x * 4 + (tid >> 6)) * 8;
    if (k0 >= KP) return;
    int n = perm_to_orig(np);
    half8 v;
#pragma unroll
    for (int j = 0; j < 8; ++j) {
        int k = k0 + j;
        float f = 0.f;
        if (k < KA) f = srcA[(size_t)n * KA + k];
        else if (k < KA + KB) f = srcB[(size_t)n * KB + (k - KA)];
        v[j] = (half_t)f;
    }
    *(half8*)(dst + wfrag(np, k0)) = v;
}

__global__ void pack_fold(half_t* __restrict__ dst, const float* __restrict__ Wih0,
                          const float* __restrict__ linW) {
    __shared__ float lw[32][128];
    __shared__ float wi[16][32];
    int nb = blockIdx.x * 16;
    int jb = blockIdx.y * 128;
    int t = threadIdx.x;
    for (int i = t; i < 32 * 128; i += 256) { int f = i >> 7, j = i & 127; lw[f][j] = linW[f * Hsz + jb + j]; }
    for (int i = t; i < 16 * 32; i += 256) { int r = i >> 5, f = i & 31; wi[r][f] = Wih0[perm_to_orig(nb + r) * 32 + f]; }
    __syncthreads();
    int r = t >> 4, j0 = (t & 15) * 8;
    half8 v;
#pragma unroll
    for (int jj = 0; jj < 8; ++jj) {
        float s = 0.f;
#pragma unroll
        for (int f = 0; f < 32; ++f) s += wi[r][f] * lw[f][j0 + jj];
        v[jj] = (half_t)s;
    }
    *(half8*)(dst + wfrag(nb + r, 1024 + jb + j0)) = v;
}

__global__ void pack_bias(float* __restrict__ b5, const float* eb0, const float* eb1,
                          const float* db0, const float* db1, const float* dWih0,
                          const float* linb) {
    int idx = blockIdx.x * 256 + threadIdx.x;
    if (idx >= 5 * NG) return;
    int which = idx >> 12, np = idx & (NG - 1);
    int n = perm_to_orig(np);
    float v;
    if (which == 0) v = eb0[n];
    else if (which == 1) v = eb1[n];
    else if (which == 2) v = db0[n];
    else if (which == 3) {
        v = db0[n];
        for (int f = 0; f < 32; ++f) v += dWih0[n * 32 + f] * linb[f];
    } else v = db1[n];
    b5[idx] = v;
}

__global__ void pack_small(half_t* __restrict__ Wlin, half_t* __restrict__ ringA0,
                           const float* __restrict__ linW, const float* __restrict__ inseq) {
    int idx = blockIdx.x * 256 + threadIdx.x;
    if (idx < 32 * Hsz) Wlin[idx] = (half_t)linW[idx];
    if (idx < Bsz * 4) {
        int b = idx >> 2, fg = idx & 3;
        half8 v;
#pragma unroll
        for (int j = 0; j < 8; ++j) v[j] = (half_t)inseq[(size_t)b * (Tsz * Fsz) + fg * 8 + j];
        *(half8*)(ringA0 + afrag(b, 1024 + fg * 8)) = v;
    }
}

// ---------------- megakernel: all 512 phases, persistent, ring buffers ----------------

struct MegaArgs {
    const float* in_seq;
    const half_t *Wenc1, *Wenc2, *Wdec1a, *Wdec1b, *Wdec2;
    const float *be1, *be2, *bd1a, *bd1b, *bd2;
    float *c0, *c1;
    half_t *ringA, *ringB, *ringD, *H1hist;
    unsigned* cnt;
};

struct PhaseDesc {
    const half_t* A; const half_t* W; const float* bias; float* c;
    half_t* h0; int cb0; half_t* h1; int cb1; half_t* h2; int cb2;
    const float* xs; half_t* xd; int K;
};

DI PhaseDesc make_desc(int p, const MegaArgs& g) {
    PhaseDesc d = {};
    if (p < 256) {
        int t = p >> 1;
        if ((p & 1) == 0) {  // enc layer0
            d.A = g.ringA + (size_t)(t & (RING - 1)) * SZA;
            d.W = g.Wenc1; d.bias = g.be1; d.c = g.c0;
            d.h0 = g.ringB + (size_t)(t & (RING - 1)) * SZB; d.cb0 = 0;
            d.h1 = g.ringA + (size_t)((t + 1) & (RING - 1)) * SZA; d.cb1 = 0;
            d.K = K1;
        } else {             // enc layer1 (+ stage x_{t+1})
            int tsel = (t + 1 < Tsz) ? t + 1 : Tsz - 1;
            d.A = g.ringB + (size_t)(t & (RING - 1)) * SZB;
            d.W = g.Wenc2; d.bias = g.be2; d.c = g.c1;
            d.h0 = g.ringB + (size_t)((t + 1) & (RING - 1)) * SZB; d.cb0 = 1024;
            d.xs = g.in_seq + (size_t)tsel * Fsz;
            d.xd = g.ringA + (size_t)((t + 1) & (RING - 1)) * SZA;
            d.K = K2;
        }
    } else {
        int t = (p - 256) >> 1;  // decoder step
        int u = 128 + t;         // global B-slot index continues from encoder
        if ((p & 1) == 0) {      // dec layer0
            if (t == 0) {        // A = [h0_enc_final | x_last] = ringA slot 128%RING
                d.A = g.ringA + (size_t)(128 & (RING - 1)) * SZA;
                d.W = g.Wdec1a; d.bias = g.bd1a; d.K = K1;
            } else {             // A = [h0_prev | h1_prev] (folded feedback)
                d.A = g.ringD + (size_t)(t & (RING - 1)) * SZB;
                d.W = g.Wdec1b; d.bias = g.bd1b; d.K = K2;
            }
            d.c = g.c0;
            d.h0 = g.ringB + (size_t)(u & (RING - 1)) * SZB; d.cb0 = 0;
            d.h1 = g.ringD + (size_t)((t + 1) & (RING - 1)) * SZB; d.cb1 = 0;
        } else {                 // dec layer1
            d.A = g.ringB + (size_t)(u & (RING - 1)) * SZB;
            d.W = g.Wdec2; d.bias = g.bd2; d.c = g.c1;
            d.h0 = g.ringB + (size_t)((u + 1) & (RING - 1)) * SZB; d.cb0 = 1024;
            d.h1 = g.ringD + (size_t)((t + 1) & (RING - 1)) * SZB; d.cb1 = 1024;
            d.h2 = g.H1hist + (size_t)t * (Bsz * Hsz); d.cb2 = 0;
            d.K = K2;
        }
    }
    return d;
}

template <int K>
DI void run_phase(const PhaseDesc& d, int mt, int nt, int tid,
                  unsigned* cnt, unsigned waitTarget,
                  float (&red)[4][64][RSTR]) {
    constexpr int CHW = (K / 32) / 4;  // k-chunks per wave: 9 (K1) or 16 (K2)
    int lane = tid & 63, w = tid >> 6;
    const half_t* pa = d.A + ((size_t)((w * CHW) * 16 + mt * 4) * 64 + lane) * 8;
    const half_t* pw = d.W + ((size_t)((w * CHW) * 256 + nt * 4) * 64 + lane) * 8;

    f32x4 acc[4][4] = {};
    half8 bA[3][4], bW[3][4];

#define LOADW(st, kk)                                                              \
    {                                                                              \
        _Pragma("unroll") for (int ni = 0; ni < 4; ++ni)                           \
            bW[st][ni] = *(const half8*)(pw + (size_t)(kk) * 131072 + ni * 512);   \
    }
#define LOADA(st, kk)                                                              \
    {                                                                              \
        _Pragma("unroll") for (int mi = 0; mi < 4; ++mi)                           \
            bA[st][mi] = *(const half8*)(pa + (size_t)(kk) * 8192 + mi * 512);     \
    }

    // W prefetch before the wait: weights are constant, barrier-independent
    LOADW(0, 0)
    LOADW(1, 1)

    if (waitTarget) {
        if (tid == 0) {
            // relaxed spin (NO acquire: an agent-acquire would buffer_inv the L2
            // and evict the resident weight panels — that was round 3's 7 GB).
            while (__hip_atomic_load(cnt, __ATOMIC_RELAXED, __HIP_MEMORY_SCOPE_AGENT) < waitTarget)
                __builtin_amdgcn_s_sleep(2);
        }
        __syncthreads();  // gates all waves' A loads behind the counter check
    }

    LOADA(0, 0)
    LOADA(1, 1)
#pragma unroll
    for (int kk = 0; kk < CHW; ++kk) {
        if (kk + 2 < CHW) { LOADW((kk + 2) % 3, kk + 2) LOADA((kk + 2) % 3, kk + 2) }
        const int st = kk % 3;
#pragma unroll
        for (int mi = 0; mi < 4; ++mi)
#pragma unroll
            for (int ni = 0; ni < 4; ++ni)
                acc[mi][ni] = __builtin_amdgcn_mfma_f32_16x16x32_f16(bA[st][mi], bW[st][ni], acc[mi][ni], 0, 0, 0);
    }
#undef LOADW
#undef LOADA

    // cross-wave K reduction via LDS
    int l15 = lane & 15, l4 = lane >> 4;
#pragma unroll
    for (int mi = 0; mi < 4; ++mi)
#pragma unroll
        for (int ni = 0; ni < 4; ++ni)
#pragma unroll
            for (int r = 0; r < 4; ++r)
                red[w][mi * 16 + l4 * 4 + r][ni * 16 + l15] = acc[mi][ni][r];
    __syncthreads();

    // fused LSTM epilogue: thread -> (1 row, 4 hidden units)
    int row = tid >> 2, q = tid & 3, jo0 = q * 4;
    f32x4 g0 = {}, g1 = {}, g2 = {}, g3 = {};
#pragma unroll
    for (int ww = 0; ww < 4; ++ww) {
        g0 += *(const f32x4*)&red[ww][row][jo0];
        g1 += *(const f32x4*)&red[ww][row][16 + jo0];
        g2 += *(const f32x4*)&red[ww][row][32 + jo0];
        g3 += *(const f32x4*)&red[ww][row][48 + jo0];
    }
    const float* bb = d.bias + nt * 64;
    g0 += *(const f32x4*)(bb + jo0);
    g1 += *(const f32x4*)(bb + 16 + jo0);
    g2 += *(const f32x4*)(bb + 32 + jo0);
    g3 += *(const f32x4*)(bb + 48 + jo0);

    int bglob = mt * 64 + row;
    int jg0 = nt * 16 + jo0;
    float* cp = d.c + (size_t)bglob * Hsz + jg0;  // single-owner: normal cached
    f32x4 cold = *(const f32x4*)cp;
    f32x4 cnew;
    half4v hv;
#pragma unroll
    for (int e = 0; e < 4; ++e) {
        float si = 1.f / (1.f + __expf(-g0[e]));
        float sf = 1.f / (1.f + __expf(-g1[e]));
        float tg = 1.f - 2.f / (__expf(2.f * g2[e]) + 1.f);
        float so = 1.f / (1.f + __expf(-g3[e]));
        float cn = sf * cold[e] + si * tg;
        cnew[e] = cn;
        float th = 1.f - 2.f / (__expf(2.f * cn) + 1.f);
        hv[e] = (half_t)(so * th);
    }
    *(f32x4*)cp = cnew;

    {
        int col = d.cb0 + jg0;
        store8_wt(d.h0 + ((size_t)((col >> 5) * 16 + (bglob >> 4)) * 64 + ((col >> 3) & 3) * 16 + (bglob & 15)) * 8 + (col & 7), hv);
    }
    if (d.h1) {
        int col = d.cb1 + jg0;
        store8_wt(d.h1 + ((size_t)((col >> 5) * 16 + (bglob >> 4)) * 64 + ((col >> 3) & 3) * 16 + (bglob & 15)) * 8 + (col & 7), hv);
    }
    if (d.h2) {  // H1hist: read only after kernel end -> normal store
        int col = d.cb2 + jg0;
        *(half4v*)(d.h2 + ((size_t)((col >> 5) * 16 + (bglob >> 4)) * 64 + ((col >> 3) & 3) * 16 + (bglob & 15)) * 8 + (col & 7)) = hv;
    }

    // stage next encoder input x (f32 -> f16 frag cols 1024..1056); nt==0 WGs only
    if (d.xs && nt == 0) {
        int f0 = q * 8;
        const float* xs = d.xs + (size_t)bglob * (Tsz * Fsz) + f0;
        half_t v[8];
#pragma unroll
        for (int j = 0; j < 8; ++j) v[j] = (half_t)xs[j];
        half4v lo = {v[0], v[1], v[2], v[3]}, hi = {v[4], v[5], v[6], v[7]};
        half_t* xp = d.xd + afrag(bglob, 1024 + f0);
        store8_wt(xp, lo);
        store8_wt(xp + 4, hi);
    }
}

__launch_bounds__(256, 1) __global__ void mega_kernel(MegaArgs g) {
    __shared__ __align__(16) float red[4][64][RSTR];  // 86 KB -> 1 block/CU
    int bid = blockIdx.x;
    // XCD swizzle: same-nt tiles (all 4 mt) land on one XCD -> W slice 4MB-max L2-resident
    int low3 = bid & 7, rest = bid >> 3;
    int mt = rest & 3, nt = ((rest >> 2) << 3) | low3;
    int tid = threadIdx.x;
    unsigned* cnt = g.cnt + mt * 64;  // one counter per row-block group (64 WGs), 256B apart

#pragma unroll 1
    for (int p = 0; p < 512; ++p) {
        PhaseDesc d = make_desc(p, g);
        if (d.K == K1) run_phase<K1>(d, mt, nt, tid, cnt, (unsigned)(64 * p), red);
        else           run_phase<K2>(d, mt, nt, tid, cnt, (unsigned)(64 * p), red);
        // arrive: syncthreads' vmcnt(0) drain completes the write-through h-stores
        // of every wave; then one relaxed agent-scope add. No fences anywhere.
        __syncthreads();
        if (tid == 0)
            __hip_atomic_fetch_add(cnt, 1u, __ATOMIC_RELAXED, __HIP_MEMORY_SCOPE_AGENT);
    }
}

// ---------------- final projection ----------------
__launch_bounds__(256, 1) __global__
void lin_out(const half_t* __restrict__ H1, const half_t* __restrict__ Wl,
             const float* __restrict__ lb, float* __restrict__ out) {
    int w = threadIdx.x >> 6, lane = threadIdx.x & 63;
    int l15 = lane & 15, l4 = lane >> 4;
    int rowt = blockIdx.x * 4 + w;
    int t = rowt >> 4, mi = rowt & 15;
    const half_t* pa = H1 + (size_t)t * (Bsz * Hsz);
    const half_t* pb0 = Wl + (size_t)l15 * Hsz + l4 * 8;
    const half_t* pb1 = Wl + (size_t)(16 + l15) * Hsz + l4 * 8;
    f32x4 ac0 = {}, ac1 = {};
#pragma unroll 4
    for (int kc = 0; kc < 32; ++kc) {
        half8 a = *(const half8*)(pa + ((size_t)(kc * 16 + mi) * 64 + lane) * 8);
        half8 b0 = *(const half8*)(pb0 + kc * 32);
        half8 b1 = *(const half8*)(pb1 + kc * 32);
        ac0 = __builtin_amdgcn_mfma_f32_16x16x32_f16(a, b0, ac0, 0, 0, 0);
        ac1 = __builtin_amdgcn_mfma_f32_16x16x32_f16(a, b1, ac1, 0, 0, 0);
    }
#pragma unroll
    for (int r = 0; r < 4; ++r) {
        int row = rowt * 16 + l4 * 4 + r;  // flat = t*256 + b
        int b = row & 255;
        size_t o = (size_t)b * (Tsz * Fsz) + t * Fsz;
        out[o + l15] = ac0[r] + lb[l15];
        out[o + 16 + l15] = ac1[r] + lb[16 + l15];
    }
}

// ---------------- host ----------------

extern "C" void kernel_launch(void* const* d_in, const int* in_sizes, int n_in,
                              void* d_out, int out_size, void* d_ws, size_t ws_size,
                              hipStream_t stream) {
    (void)in_sizes; (void)n_in;
    const float* in_seq = (const float*)d_in[0];
    const float* eWih0 = (const float*)d_in[1];
    const float* eWhh0 = (const float*)d_in[2];
    const float* eb0 = (const float*)d_in[3];
    const float* eWih1 = (const float*)d_in[4];
    const float* eWhh1 = (const float*)d_in[5];
    const float* eb1 = (const float*)d_in[6];
    const float* dWih0 = (const float*)d_in[7];
    const float* dWhh0 = (const float*)d_in[8];
    const float* db0 = (const float*)d_in[9];
    const float* dWih1 = (const float*)d_in[10];
    const float* dWhh1 = (const float*)d_in[11];
    const float* db1 = (const float*)d_in[12];
    const float* linW = (const float*)d_in[13];
    const float* linb = (const float*)d_in[14];
    float* out = (float*)d_out;

    char* base = (char*)d_ws;
    size_t off = 0;
    auto alloc = [&](size_t bytes) {
        char* r = base + off;
        off = (off + bytes + 255) & ~(size_t)255;
        return r;
    };
    half_t* Wenc1 = (half_t*)alloc((size_t)NG * K1 * 2);
    half_t* Wenc2 = (half_t*)alloc((size_t)NG * K2 * 2);
    half_t* Wdec1a = (half_t*)alloc((size_t)NG * K1 * 2);
    half_t* Wdec1b = (half_t*)alloc((size_t)NG * K2 * 2);
    half_t* Wdec2 = (half_t*)alloc((size_t)NG * K2 * 2);
    half_t* Wlin = (half_t*)alloc((size_t)32 * Hsz * 2);
    float* bias5 = (float*)alloc((size_t)5 * NG * 4);
    float* c0 = (float*)alloc((size_t)Bsz * Hsz * 4);
    float* c1 = (float*)alloc((size_t)Bsz * Hsz * 4);
    half_t* ringA = (half_t*)alloc((size_t)RING * SZA * 2);  // 18 MB
    half_t* ringB = (half_t*)alloc((size_t)RING * SZB * 2);  // 32 MB
    half_t* ringD = (half_t*)alloc((size_t)RING * SZB * 2);  // 32 MB
    half_t* H1hist = (half_t*)alloc((size_t)Tsz * Bsz * Hsz * 2);
    unsigned* barCnt = (unsigned*)alloc(4 * 64 * sizeof(unsigned));

    if (off > ws_size) {  // clean failure signature: all-zero output
        hipMemsetAsync(d_out, 0, (size_t)out_size * 4, stream);
        return;
    }

    float* be1 = bias5;
    float* be2 = bias5 + NG;
    float* bd1a = bias5 + 2 * NG;
    float* bd1b = bias5 + 3 * NG;
    float* bd2 = bias5 + 4 * NG;

    // ---- prep (re-run every call; graph-replay safe) ----
    hipMemsetAsync(c0, 0, (size_t)Bsz * Hsz * 4, stream);
    hipMemsetAsync(c1, 0, (size_t)Bsz * Hsz * 4, stream);
    hipMemsetAsync(ringA, 0, (size_t)RING * SZA * 2, stream);  // zero h0/x/pad everywhere
    hipMemsetAsync(ringB, 0, (size_t)SZB * 2, stream);         // slot 0: zero h1 init
    hipMemsetAsync(barCnt, 0, 4 * 64 * sizeof(unsigned), stream);

    pack_cat<<<dim3(K1 / 32, NG / 64), 256, 0, stream>>>(Wenc1, eWhh0, 1024, eWih0, 32, K1);
    pack_cat<<<dim3(K2 / 32, NG / 64), 256, 0, stream>>>(Wenc2, eWih1, 1024, eWhh1, 1024, K2);
    pack_cat<<<dim3(K1 / 32, NG / 64), 256, 0, stream>>>(Wdec1a, dWhh0, 1024, dWih0, 32, K1);
    pack_cat<<<dim3(K2 / 32, NG / 64), 256, 0, stream>>>(Wdec1b, dWhh0, 1024, nullptr, 0, K2);
    pack_fold<<<dim3(NG / 16, 1024 / 128), 256, 0, stream>>>(Wdec1b, dWih0, linW);
    pack_cat<<<dim3(K2 / 32, NG / 64), 256, 0, stream>>>(Wdec2, dWih1, 1024, dWhh1, 1024, K2);
    pack_bias<<<(5 * NG + 255) / 256, 256, 0, stream>>>(bias5, eb0, eb1, db0, db1, dWih0, linb);
    pack_small<<<128, 256, 0, stream>>>(Wlin, ringA, linW, in_seq);

    // ---- all 512 recurrent phases in one cooperative kernel ----
    MegaArgs ma;
    ma.in_seq = in_seq;
    ma.Wenc1 = Wenc1; ma.Wenc2 = Wenc2;
    ma.Wdec1a = Wdec1a; ma.Wdec1b = Wdec1b; ma.Wdec2 = Wdec2;
    ma.be1 = be1; ma.be2 = be2; ma.bd1a = bd1a; ma.bd1b = bd1b; ma.bd2 = bd2;
    ma.c0 = c0; ma.c1 = c1;
    ma.ringA = ringA; ma.ringB = ringB; ma.ringD = ringD;
    ma.H1hist = H1hist;
    ma.cnt = barCnt;
    void* kargs[] = {&ma};
    hipLaunchCooperativeKernel((const void*)mega_kernel, dim3(256), dim3(256), kargs, 0, stream);

    lin_out<<<512, 256, 0, stream>>>(H1hist, Wlin, linb, out);
}